// Round 7
// baseline (172.493 us; speedup 1.0000x reference)
//
#include <hip/hip_runtime.h>
#include <math.h>

#define B_ 8
#define C_ 512
#define L_ 1024
#define NH_ 8
#define DH_ 64
#define EPS 1e-5f
#define SCALE 0.125f
#define QSCALE (0.125f * 1.44269504088896f)   // fold log2(e) into q so p = exp2(s)

typedef __bf16 bf16x8 __attribute__((ext_vector_type(8)));
typedef __bf16 bf16x4 __attribute__((ext_vector_type(4)));
typedef float  f32x4  __attribute__((ext_vector_type(4)));
typedef float  f32x16 __attribute__((ext_vector_type(16)));

#define MFMA16(a, b, c) __builtin_amdgcn_mfma_f32_16x16x32_bf16((a), (b), (c), 0, 0, 0)
#define MFMA32(a, b, c) __builtin_amdgcn_mfma_f32_32x32x16_bf16((a), (b), (c), 0, 0, 0)

// async global->LDS, 16B per lane, dest = wave-uniform base + lane*16
__device__ __forceinline__ void glds16(const __bf16* g, __bf16* l) {
    __builtin_amdgcn_global_load_lds((const __attribute__((address_space(1))) void*)(g),
                                     (__attribute__((address_space(3))) void*)(l),
                                     16, 0, 0);
}

// ---------------------------------------------------------------------------
// prep: blocks [0,1024): weight fp32->bf16 (Wq|Wkv|Wo). blocks [1024,1280):
// GroupNorm stats, one block per (b,g) -> stats[bg] = {mean, rstd}.
// ---------------------------------------------------------------------------
__global__ __launch_bounds__(256)
void prep_kernel(const float* __restrict__ Wq, const float* __restrict__ Wkv,
                 const float* __restrict__ Wo, __bf16* __restrict__ dst,
                 const float* __restrict__ x, float* __restrict__ stats) {
    __shared__ float rs[256], rss[256];
    int bid = blockIdx.x, tid = threadIdx.x;
    if (bid < 1024) {
        int idx = bid * 256 + tid;              // float4 index, total 262144
        float4 v;
        if (idx < 65536)        v = ((const float4*)Wq)[idx];
        else if (idx < 196608)  v = ((const float4*)Wkv)[idx - 65536];
        else                    v = ((const float4*)Wo)[idx - 196608];
        bf16x4 o;
        o[0] = (__bf16)v.x; o[1] = (__bf16)v.y; o[2] = (__bf16)v.z; o[3] = (__bf16)v.w;
        ((bf16x4*)dst)[idx] = o;
        return;
    }
    int bg = bid - 1024;
    size_t goff = (size_t)bg * 16 * L_;         // contiguous group span
    const float4* x4 = (const float4*)(x + goff);
    float s = 0.f, ss = 0.f;
    for (int i = tid; i < 4096; i += 256) {
        float4 v = x4[i];
        s  += v.x + v.y + v.z + v.w;
        ss += v.x * v.x + v.y * v.y + v.z * v.z + v.w * v.w;
    }
    rs[tid] = s; rss[tid] = ss;
    __syncthreads();
    for (int off = 128; off > 0; off >>= 1) {
        if (tid < off) { rs[tid] += rs[tid + off]; rss[tid] += rss[tid + off]; }
        __syncthreads();
    }
    if (tid == 0) {
        const float inv_n = 1.f / 16384.f;
        float mean = rs[0] * inv_n;
        float var  = rss[0] * inv_n - mean * mean;
        stats[bg * 2]     = mean;
        stats[bg * 2 + 1] = rsqrtf(var + EPS);
    }
}

// ---------------------------------------------------------------------------
// GroupNorm apply + transpose: block per (b, 32-l tile). Coalesced fp32 reads,
// LDS [l][c] tile (pad 520), coalesced 1-KB bf16x8 writes of hnT[b][l][c].
// ---------------------------------------------------------------------------
__global__ __launch_bounds__(256)
void gn_apply_kernel(const float* __restrict__ x, const float* __restrict__ gamma,
                     const float* __restrict__ beta, const float* __restrict__ stats,
                     __bf16* __restrict__ hnT) {
    __shared__ __bf16 T[32 * 520];
    const int lt = blockIdx.x, b = blockIdx.y;
    const int tid = threadIdx.x;
    const int l0 = lt * 32;
    const int cbase = tid >> 3, fl = tid & 7;
#pragma unroll
    for (int p = 0; p < 16; ++p) {
        int cc = cbase + p * 32;
        float4 v = *(const float4*)&x[((size_t)b * C_ + cc) * L_ + l0 + fl * 4];
        int bg = b * 32 + (cc >> 4);
        float m = stats[bg * 2], rstd = stats[bg * 2 + 1];
        float ga = gamma[cc] * rstd, be = beta[cc];
        T[(fl * 4 + 0) * 520 + cc] = (__bf16)((v.x - m) * ga + be);
        T[(fl * 4 + 1) * 520 + cc] = (__bf16)((v.y - m) * ga + be);
        T[(fl * 4 + 2) * 520 + cc] = (__bf16)((v.z - m) * ga + be);
        T[(fl * 4 + 3) * 520 + cc] = (__bf16)((v.w - m) * ga + be);
    }
    __syncthreads();
    const int lrow = tid >> 6, cu = tid & 63;
#pragma unroll
    for (int pp = 0; pp < 8; ++pp) {
        int l = pp * 4 + lrow;
        bf16x8 r = *(const bf16x8*)&T[l * 520 + cu * 8];
        *(bf16x8*)&hnT[((size_t)b * L_ + l0 + l) * C_ + cu * 8] = r;
    }
}

// ---------------------------------------------------------------------------
// Shared MFMA GEMM main loop — m97-structure: SINGLE-buffered 32-KB LDS,
// 2 barriers per K-step, implicit wave-level overlap at ~3-4 blocks/CU
// (m97: 912 TF vs m132's 508 TF at 64-KB dbuf / 2 blocks/CU). A,B:
// [rows][512] bf16 K-contig. 128x128 tile, 4 waves (2x2), BK=64.
// ---------------------------------------------------------------------------
__device__ __forceinline__
void gemm_mainloop(const __bf16* __restrict__ A, const __bf16* __restrict__ Bp,
                   __bf16* As, __bf16* Bs, f32x4 acc[4][4]) {
    const int tid = threadIdx.x;
    const int lane = tid & 63, w = tid >> 6;
    const int c = lane & 15, q = lane >> 4;
    const int wm = (w >> 1) * 64, wn = (w & 1) * 64;
    const int l8 = lane >> 3, kgsw = (lane & 7) ^ l8;

    for (int k0 = 0; k0 < 512; k0 += 64) {
#pragma unroll
        for (int i = 0; i < 4; ++i) {
            int chunk = w * 4 + i;              // 16 chunks of 8 rows
            int row = chunk * 8 + l8;
            glds16(A  + (size_t)row * 512 + k0 + kgsw * 8, &As[chunk * 512]);
            glds16(Bp + (size_t)row * 512 + k0 + kgsw * 8, &Bs[chunk * 512]);
        }
        __syncthreads();
#pragma unroll
        for (int ks = 0; ks < 2; ++ks) {
            const int koff = ((ks * 4 + q) ^ (c & 7)) * 8;
            bf16x8 af[4], bfr[4];
#pragma unroll
            for (int m = 0; m < 4; ++m)
                af[m] = *(const bf16x8*)&As[(wm + m * 16 + c) * 64 + koff];
#pragma unroll
            for (int n = 0; n < 4; ++n)
                bfr[n] = *(const bf16x8*)&Bs[(wn + n * 16 + c) * 64 + koff];
#pragma unroll
            for (int m = 0; m < 4; ++m)
#pragma unroll
                for (int n = 0; n < 4; ++n)
                    acc[m][n] = MFMA16(af[m], bfr[n], acc[m][n]);
        }
        __syncthreads();
    }
}

// ---------------------------------------------------------------------------
// QKV projection. sec 0: q=(Wq hn+bq)*QSCALE -> qT[b][h][l][d]
//                 sec 1: k=(Wkv[0:512] hn+bkv)*SCALE -> kT
//                 sec 2: v=Wkv[512:] hn+bkv[512:] -> v[b][c][l]
// Flat 768-block grid, bijective XCD swizzle: XCD x gets exactly batch x's
// 96 tiles (hn 1 MB + weights L2-resident per XCD). 32-KB LDS -> 3+ blocks/CU
// -> 768 blocks run in ONE tail-free round (768 = 3 x 256 CUs).
// ---------------------------------------------------------------------------
__global__ __launch_bounds__(256)
void qkv_kernel(const __bf16* __restrict__ Wq_bf, const __bf16* __restrict__ Wkv_bf,
                const __bf16* __restrict__ hnT,
                const float* __restrict__ bq, const float* __restrict__ bkv,
                __bf16* __restrict__ qT, __bf16* __restrict__ kT,
                __bf16* __restrict__ vv) {
    __shared__ __bf16 SMEM[128 * 64 * 2];       // As|Bs, reused as T2[128][128]
    __bf16* As = SMEM;
    __bf16* Bs = SMEM + 128 * 64;
    const int bid = blockIdx.x;
    const int wgid = (bid & 7) * 96 + (bid >> 3);   // XCD x -> [x*96, x*96+96)
    const int b = wgid / 96;                        // == XCD id
    const int xx = wgid % 96;
    const int sec = xx >> 5, t = xx & 31;
    const __bf16* hb = hnT + (size_t)b * L_ * C_;

    const __bf16 *A, *Bp;
    int m0, n0;
    if (sec < 2) {
        m0 = (t & 3) * 128; n0 = (t >> 2) * 128;    // m=o, n=l
        A  = (sec == 0 ? Wq_bf : Wkv_bf) + (size_t)m0 * 512;
        Bp = hb + (size_t)n0 * 512;
    } else {
        m0 = (t >> 2) * 128; n0 = (t & 3) * 128;    // m=l, n=o
        A  = hb + (size_t)m0 * 512;
        Bp = Wkv_bf + (size_t)(512 + n0) * 512;
    }

    f32x4 acc[4][4];
#pragma unroll
    for (int m = 0; m < 4; ++m)
#pragma unroll
        for (int n = 0; n < 4; ++n)
#pragma unroll
            for (int r = 0; r < 4; ++r) acc[m][n][r] = 0.f;

    gemm_mainloop(A, Bp, As, Bs, acc);          // ends with __syncthreads()

    const int tid = threadIdx.x, lane = tid & 63, w = tid >> 6;
    const int c = lane & 15, q = lane >> 4;
    const int wm = (w >> 1) * 64, wn = (w & 1) * 64;

    __bf16* T2 = SMEM;                          // [n_loc 128][m 128], xor-swz
    const float* bias = (sec == 0) ? bq : bkv;
    const float scl = (sec == 0) ? QSCALE : SCALE;
#pragma unroll
    for (int mt = 0; mt < 4; ++mt)
#pragma unroll
        for (int nt = 0; nt < 4; ++nt) {
            int n_loc = wn + nt * 16 + c;
            int u4 = (wm >> 2) + mt * 4 + q;    // 4-elem unit over m
            int u4sw = u4 ^ ((n_loc & 7) << 1);
            bf16x4 ov;
            if (sec < 2) {
                int ob = m0 + wm + mt * 16 + q * 4;
#pragma unroll
                for (int r = 0; r < 4; ++r)
                    ov[r] = (__bf16)((acc[mt][nt][r] + bias[ob + r]) * scl);
            } else {
                float bi = bkv[512 + n0 + n_loc];
#pragma unroll
                for (int r = 0; r < 4; ++r)
                    ov[r] = (__bf16)(acc[mt][nt][r] + bi);
            }
            *(bf16x4*)&T2[n_loc * 128 + u4sw * 4] = ov;
        }
    __syncthreads();
#pragma unroll
    for (int p = 0; p < 8; ++p) {
        int rrow = p * 16 + (tid >> 4);         // n_loc
        int u16 = tid & 15;                     // 8-elem unit over m
        int u4p = (u16 * 2) ^ ((rrow & 7) << 1);
        bf16x8 val = *(const bf16x8*)&T2[rrow * 128 + u4p * 4];
        if (sec < 2) {
            int l = n0 + rrow;
            int og = m0 + u16 * 8;
            int hh = og >> 6, d0 = og & 63;
            __bf16* dstp = (sec == 0) ? qT : kT;
            *(bf16x8*)&dstp[((size_t)(b * NH_ + hh) * L_ + l) * DH_ + d0] = val;
        } else {
            int o = n0 + rrow;
            int lg = m0 + u16 * 8;
            *(bf16x8*)&vv[((size_t)b * C_ + o) * L_ + lg] = val;
        }
    }
}

// ---------------------------------------------------------------------------
// Flash attention v7: 32x32x16 MFMA, in-register softmax, Q direct
// global->register. K/V DOUBLE-buffered (32 KB LDS total) with the R1/R2-
// proven protocol: compute buf(it&1); B1 (reads done); stage it+2 into the
// just-freed buf; vmcnt(4) retires tile it+1; B2 (resident). 32 KB +
// __launch_bounds__(256,3) -> 3 blocks/CU = 12 waves/CU (was 8).
// l via ones-row MFMA. Flat 512-block grid, batch b -> XCD b (K/V L2-local).
// ---------------------------------------------------------------------------
__global__ __launch_bounds__(256, 3)
void attn_kernel(const __bf16* __restrict__ qT, const __bf16* __restrict__ kT,
                 const __bf16* __restrict__ vv, __bf16* __restrict__ aoT) {
    const int bid = blockIdx.x;
    const int wg = (bid & 7) * 64 + (bid >> 3);     // XCD x -> wg in [x*64,x*64+64)
    const int tt = wg & 7, h = (wg >> 3) & 7, b = wg >> 6;   // b == XCD id
    const int t0 = tt * 128;
    __shared__ __bf16 Ks[2][64 * 64];    // [s][d]  16 KB dbuf
    __shared__ __bf16 Vs[2][64 * 64];    // [d][s]  16 KB dbuf

    const int tid = threadIdx.x, lane = tid & 63, w = tid >> 6;
    const int l8 = lane >> 3, kg = (lane & 7) ^ l8;
    const int ln = lane & 31, hi = lane >> 5, r7 = ln & 7;

    const __bf16* qbase = qT + ((size_t)(b * NH_ + h) * L_ + t0) * DH_;
    const __bf16* kbase = kT + (size_t)(b * NH_ + h) * L_ * DH_;
    const __bf16* vbase = vv + (size_t)(b * C_ + h * DH_) * L_;

    // Q direct to registers: 4 x 16B per lane (L2-hot, qkv just wrote it)
    const int qrow = w * 32 + ln;
    bf16x8 qf[4];
#pragma unroll
    for (int ks = 0; ks < 4; ++ks)
        qf[ks] = *(const bf16x8*)&qbase[(size_t)qrow * DH_ + (ks * 2 + hi) * 8];

    // prefetch K/V tiles 0,1 (2 K-chunks + 2 V-chunks per wave per tile)
#pragma unroll
    for (int buf = 0; buf < 2; ++buf)
#pragma unroll
        for (int i = 0; i < 2; ++i) {
            int chunk = w * 2 + i, row = chunk * 8 + l8;
            glds16(kbase + (size_t)(buf * 64 + row) * DH_ + kg * 8, &Ks[buf][chunk * 512]);
            glds16(vbase + (size_t)row * L_ + buf * 64 + kg * 8, &Vs[buf][chunk * 512]);
        }
    // outstanding: Q(4) + 8 glds16. Retire Q + tile0 (8 oldest); keep tile1.
    asm volatile("s_waitcnt vmcnt(4)" ::: "memory");
    asm volatile("s_barrier" ::: "memory");

    bf16x8 aOnes;                               // A row 0 = ones (l = 1 . P)
    {
        __bf16 one = (__bf16)((ln == 0) ? 1.f : 0.f);
#pragma unroll
        for (int j = 0; j < 8; ++j) aOnes[j] = one;
    }

    f32x16 o_acc[2], o_l;
#pragma unroll
    for (int dt = 0; dt < 2; ++dt)
#pragma unroll
        for (int r = 0; r < 16; ++r) o_acc[dt][r] = 0.f;
#pragma unroll
    for (int r = 0; r < 16; ++r) o_l[r] = 0.f;

    for (int it = 0; it < 16; ++it) {
        const __bf16* Kc = &Ks[it & 1][0];
        const __bf16* Vc = &Vs[it & 1][0];

        // S^T[s][t]: A=K[s][d], B=Q(frags in reg). lane: t=ln, s rows in regs.
        f32x16 sres[2];
#pragma unroll
        for (int mt = 0; mt < 2; ++mt)
#pragma unroll
            for (int r = 0; r < 16; ++r) sres[mt][r] = 0.f;
        __builtin_amdgcn_s_setprio(1);
#pragma unroll
        for (int ks = 0; ks < 4; ++ks) {
#pragma unroll
            for (int mt = 0; mt < 2; ++mt) {
                bf16x8 aK = *(const bf16x8*)&Kc[(mt * 32 + ln) * 64 + ((ks * 2 + hi) ^ r7) * 8];
                sres[mt] = MFMA32(aK, qf[ks], sres[mt]);
            }
        }
        __builtin_amdgcn_s_setprio(0);

        // p = exp2(s); build PV B-fragments in-register.
        // reg r of sres[mt]: s = mt*32 + (r&3) + 8*(r>>2) + 4*hi
        bf16x8 frag[4];
#pragma unroll
        for (int mt = 0; mt < 2; ++mt) {
            float pv[16];
#pragma unroll
            for (int r = 0; r < 16; ++r) pv[r] = exp2f(sres[mt][r]);
            unsigned int P[8];
#pragma unroll
            for (int j = 0; j < 8; ++j)
                asm("v_cvt_pk_bf16_f32 %0, %1, %2" : "=v"(P[j]) : "v"(pv[2 * j]), "v"(pv[2 * j + 1]));
            // after swap: lanes l / l+32 hold complementary s-rows of same t
            asm("v_permlane32_swap_b32 %0, %1" : "+v"(P[0]), "+v"(P[2]));
            asm("v_permlane32_swap_b32 %0, %1" : "+v"(P[1]), "+v"(P[3]));
            asm("v_permlane32_swap_b32 %0, %1" : "+v"(P[4]), "+v"(P[6]));
            asm("v_permlane32_swap_b32 %0, %1" : "+v"(P[5]), "+v"(P[7]));
            union FU { unsigned int u[4]; bf16x8 v; } fa, fb;
            fa.u[0] = P[0]; fa.u[1] = P[1]; fa.u[2] = P[2]; fa.u[3] = P[3];
            fb.u[0] = P[4]; fb.u[1] = P[5]; fb.u[2] = P[6]; fb.u[3] = P[7];
            frag[mt * 2 + 0] = fa.v;            // k = s in [mt*32, mt*32+16)
            frag[mt * 2 + 1] = fb.v;            // k = s in [mt*32+16, mt*32+32)
        }

        // PV: O^T[d][t] += V[d][s] P[t][s];  l[t] += 1 . P[t][:] (row 0)
        __builtin_amdgcn_s_setprio(1);
#pragma unroll
        for (int ks2 = 0; ks2 < 4; ++ks2) {
#pragma unroll
            for (int dt = 0; dt < 2; ++dt) {
                bf16x8 aV = *(const bf16x8*)&Vc[(dt * 32 + ln) * 64 + ((ks2 * 2 + hi) ^ r7) * 8];
                o_acc[dt] = MFMA32(aV, frag[ks2], o_acc[dt]);
            }
            o_l = MFMA32(aOnes, frag[ks2], o_l);
        }
        __builtin_amdgcn_s_setprio(0);

        // B1: all waves done reading buf (it&1) -> safe to overwrite
        asm volatile("s_barrier" ::: "memory");
        if (it < 14) {
            int s0n = (it + 2) * 64;
            __bf16* Kw = &Ks[it & 1][0];
            __bf16* Vw = &Vs[it & 1][0];
#pragma unroll
            for (int i = 0; i < 2; ++i) {
                int chunk = w * 2 + i, row = chunk * 8 + l8;
                glds16(kbase + (size_t)(s0n + row) * DH_ + kg * 8, &Kw[chunk * 512]);
                glds16(vbase + (size_t)row * L_ + s0n + kg * 8, &Vw[chunk * 512]);
            }
            // retire tile it+1 (oldest 4 of 8); keep the 4 just issued
            asm volatile("s_waitcnt vmcnt(4)" ::: "memory");
        } else {
            asm volatile("s_waitcnt vmcnt(0)" ::: "memory");
        }
        asm volatile("s_barrier" ::: "memory");   // B2: tile it+1 resident
    }

    // l[t=ln] sits in reg 0 of lane ln (hi=0 rows of the ones-MFMA output)
    float lsum = __shfl(o_l[0], ln);
    float linv = 1.f / lsum;
    const int tg = t0 + w * 32 + ln;
    __bf16* aobase = aoT + ((size_t)b * L_ + tg) * C_ + h * DH_;
#pragma unroll
    for (int dt = 0; dt < 2; ++dt)
#pragma unroll
        for (int rq = 0; rq < 4; ++rq) {
            bf16x4 ov;
#pragma unroll
            for (int j = 0; j < 4; ++j) ov[j] = (__bf16)(o_acc[dt][rq * 4 + j] * linv);
            *(bf16x4*)&aobase[dt * 32 + rq * 8 + hi * 4] = ov;
        }
}

// ---------------------------------------------------------------------------
// Output projection + bias + residual: D[m=l][n=o], A=aoT, B=Wo. fp32 out.
// Flat 256-block grid, bijective XCD swizzle: XCD x gets batch x's 32 tiles.
// 32-KB LDS -> one block per CU, tail-free.
// ---------------------------------------------------------------------------
__global__ __launch_bounds__(256)
void proj_kernel(const __bf16* __restrict__ aoT, const __bf16* __restrict__ Wo_bf,
                 const float* __restrict__ bo, const float* __restrict__ x,
                 float* __restrict__ out) {
    __shared__ __bf16 As[128 * 64], Bs[128 * 64];
    const int bid = blockIdx.x;
    const int wgid = (bid & 7) * 32 + (bid >> 3);   // XCD x -> [x*32, x*32+32)
    const int b = wgid >> 5, t = wgid & 31;         // b == XCD id
    const int m0 = (t >> 2) * 128;   // l
    const int n0 = (t & 3) * 128;    // o
    const __bf16* A  = aoT + (size_t)b * L_ * C_ + (size_t)m0 * 512;
    const __bf16* Bp = Wo_bf + (size_t)n0 * 512;

    f32x4 acc[4][4];
#pragma unroll
    for (int m = 0; m < 4; ++m)
#pragma unroll
        for (int n = 0; n < 4; ++n)
#pragma unroll
            for (int r = 0; r < 4; ++r) acc[m][n][r] = 0.f;

    gemm_mainloop(A, Bp, As, Bs, acc);

    const int tid = threadIdx.x, lane = tid & 63, w = tid >> 6;
    const int c = lane & 15, q = lane >> 4;
    const int wm = (w >> 1) * 64, wn = (w & 1) * 64;

#pragma unroll
    for (int mt = 0; mt < 4; ++mt)
#pragma unroll
        for (int nt = 0; nt < 4; ++nt) {
            int lb = m0 + wm + mt * 16 + q * 4;  // 4 consecutive l
            int o  = n0 + wn + nt * 16 + c;
            float bi = bo[o];
            size_t off = ((size_t)b * C_ + o) * L_ + lb;
            float4 xv = *(const float4*)&x[off];
            float4 rv;
            rv.x = acc[mt][nt][0] + bi + xv.x;
            rv.y = acc[mt][nt][1] + bi + xv.y;
            rv.z = acc[mt][nt][2] + bi + xv.z;
            rv.w = acc[mt][nt][3] + bi + xv.w;
            *(float4*)&out[off] = rv;
        }
}

// ---------------------------------------------------------------------------
extern "C" void kernel_launch(void* const* d_in, const int* in_sizes, int n_in,
                              void* d_out, int out_size, void* d_ws, size_t ws_size,
                              hipStream_t stream) {
    const float* x     = (const float*)d_in[0];
    const float* gamma = (const float*)d_in[1];
    const float* beta  = (const float*)d_in[2];
    const float* Wq    = (const float*)d_in[3];
    const float* bq    = (const float*)d_in[4];
    const float* Wkv   = (const float*)d_in[5];
    const float* bkv   = (const float*)d_in[6];
    const float* Wo    = (const float*)d_in[7];
    const float* bo    = (const float*)d_in[8];
    float* out = (float*)d_out;

    __bf16* wsb = (__bf16*)d_ws;
    __bf16* Wq_bf  = wsb;                        // 262144
    __bf16* Wkv_bf = wsb + 262144;               // 524288
    __bf16* Wo_bf  = wsb + 786432;               // 262144
    __bf16* hnT    = wsb + 1048576;              // 4 Mi
    __bf16* qT     = wsb + 5242880;              // 4 Mi
    __bf16* kT     = wsb + 9437184;              // 4 Mi
    __bf16* vv     = wsb + 13631488;             // 4 Mi
    __bf16* aoT    = wsb + 17825792;             // 4 Mi
    float*  stats  = (float*)(wsb + 22020096);   // 512 floats

    prep_kernel<<<dim3(1280), 256, 0, stream>>>(Wq, Wkv, Wo, wsb, x, stats);
    gn_apply_kernel<<<dim3(32, B_), 256, 0, stream>>>(x, gamma, beta, stats, hnT);
    qkv_kernel<<<dim3(768), 256, 0, stream>>>(Wq_bf, Wkv_bf, hnT, bq, bkv, qT, kT, vv);
    attn_kernel<<<dim3(512), 256, 0, stream>>>(qT, kT, vv, aoT);
    proj_kernel<<<dim3(256), 256, 0, stream>>>(aoT, Wo_bf, bo, x, out);
}

// Round 8
// 159.747 us; speedup vs baseline: 1.0798x; 1.0798x over previous
//
#include <hip/hip_runtime.h>
#include <math.h>

#define B_ 8
#define C_ 512
#define L_ 1024
#define NH_ 8
#define DH_ 64
#define EPS 1e-5f
#define SCALE 0.125f
#define QSCALE (0.125f * 1.44269504088896f)   // fold log2(e) into q so p = exp2(s)

typedef __bf16 bf16x8 __attribute__((ext_vector_type(8)));
typedef __bf16 bf16x4 __attribute__((ext_vector_type(4)));
typedef float  f32x4  __attribute__((ext_vector_type(4)));
typedef float  f32x16 __attribute__((ext_vector_type(16)));

#define MFMA16(a, b, c) __builtin_amdgcn_mfma_f32_16x16x32_bf16((a), (b), (c), 0, 0, 0)
#define MFMA32(a, b, c) __builtin_amdgcn_mfma_f32_32x32x16_bf16((a), (b), (c), 0, 0, 0)

// async global->LDS, 16B per lane, dest = wave-uniform base + lane*16
__device__ __forceinline__ void glds16(const __bf16* g, __bf16* l) {
    __builtin_amdgcn_global_load_lds((const __attribute__((address_space(1))) void*)(g),
                                     (__attribute__((address_space(3))) void*)(l),
                                     16, 0, 0);
}

// ---------------------------------------------------------------------------
// prep: blocks [0,1024): weight fp32->bf16 (Wq|Wkv|Wo). blocks [1024,1280):
// GroupNorm stats, one block per (b,g) -> stats[bg] = {mean, rstd}.
// ---------------------------------------------------------------------------
__global__ __launch_bounds__(256)
void prep_kernel(const float* __restrict__ Wq, const float* __restrict__ Wkv,
                 const float* __restrict__ Wo, __bf16* __restrict__ dst,
                 const float* __restrict__ x, float* __restrict__ stats) {
    __shared__ float rs[256], rss[256];
    int bid = blockIdx.x, tid = threadIdx.x;
    if (bid < 1024) {
        int idx = bid * 256 + tid;              // float4 index, total 262144
        float4 v;
        if (idx < 65536)        v = ((const float4*)Wq)[idx];
        else if (idx < 196608)  v = ((const float4*)Wkv)[idx - 65536];
        else                    v = ((const float4*)Wo)[idx - 196608];
        bf16x4 o;
        o[0] = (__bf16)v.x; o[1] = (__bf16)v.y; o[2] = (__bf16)v.z; o[3] = (__bf16)v.w;
        ((bf16x4*)dst)[idx] = o;
        return;
    }
    int bg = bid - 1024;
    size_t goff = (size_t)bg * 16 * L_;         // contiguous group span
    const float4* x4 = (const float4*)(x + goff);
    float s = 0.f, ss = 0.f;
    for (int i = tid; i < 4096; i += 256) {
        float4 v = x4[i];
        s  += v.x + v.y + v.z + v.w;
        ss += v.x * v.x + v.y * v.y + v.z * v.z + v.w * v.w;
    }
    rs[tid] = s; rss[tid] = ss;
    __syncthreads();
    for (int off = 128; off > 0; off >>= 1) {
        if (tid < off) { rs[tid] += rs[tid + off]; rss[tid] += rss[tid + off]; }
        __syncthreads();
    }
    if (tid == 0) {
        const float inv_n = 1.f / 16384.f;
        float mean = rs[0] * inv_n;
        float var  = rss[0] * inv_n - mean * mean;
        stats[bg * 2]     = mean;
        stats[bg * 2 + 1] = rsqrtf(var + EPS);
    }
}

// ---------------------------------------------------------------------------
// GroupNorm apply + transpose: block per (b, 32-l tile). Coalesced fp32 reads,
// LDS [l][c] tile (pad 520), coalesced 1-KB bf16x8 writes of hnT[b][l][c].
// ---------------------------------------------------------------------------
__global__ __launch_bounds__(256)
void gn_apply_kernel(const float* __restrict__ x, const float* __restrict__ gamma,
                     const float* __restrict__ beta, const float* __restrict__ stats,
                     __bf16* __restrict__ hnT) {
    __shared__ __bf16 T[32 * 520];
    const int lt = blockIdx.x, b = blockIdx.y;
    const int tid = threadIdx.x;
    const int l0 = lt * 32;
    const int cbase = tid >> 3, fl = tid & 7;
#pragma unroll
    for (int p = 0; p < 16; ++p) {
        int cc = cbase + p * 32;
        float4 v = *(const float4*)&x[((size_t)b * C_ + cc) * L_ + l0 + fl * 4];
        int bg = b * 32 + (cc >> 4);
        float m = stats[bg * 2], rstd = stats[bg * 2 + 1];
        float ga = gamma[cc] * rstd, be = beta[cc];
        T[(fl * 4 + 0) * 520 + cc] = (__bf16)((v.x - m) * ga + be);
        T[(fl * 4 + 1) * 520 + cc] = (__bf16)((v.y - m) * ga + be);
        T[(fl * 4 + 2) * 520 + cc] = (__bf16)((v.z - m) * ga + be);
        T[(fl * 4 + 3) * 520 + cc] = (__bf16)((v.w - m) * ga + be);
    }
    __syncthreads();
    const int lrow = tid >> 6, cu = tid & 63;
#pragma unroll
    for (int pp = 0; pp < 8; ++pp) {
        int l = pp * 4 + lrow;
        bf16x8 r = *(const bf16x8*)&T[l * 520 + cu * 8];
        *(bf16x8*)&hnT[((size_t)b * L_ + l0 + l) * C_ + cu * 8] = r;
    }
}

// ---------------------------------------------------------------------------
// Shared MFMA GEMM main loop (R3-R6 proven): double-buffered LDS + counted
// vmcnt (prefetch depth 2, never drain to 0 in-loop), raw s_barrier. A,B:
// [rows][512] bf16 K-contig. 128x128 tile, 4 waves (2x2), BK=64.
// As/Bs each 2 x 128x64 (total 64 KB). Ends with a full barrier.
// (R7 measured the single-buffered variant: qkv 43.4 us vs ~31 -- the
//  per-step vmcnt(0) drain dominates at only 8 K-steps. Keep dbuf.)
// ---------------------------------------------------------------------------
__device__ __forceinline__
void gemm_mainloop(const __bf16* __restrict__ A, const __bf16* __restrict__ Bp,
                   __bf16* As, __bf16* Bs, f32x4 acc[4][4]) {
    const int tid = threadIdx.x;
    const int lane = tid & 63, w = tid >> 6;
    const int c = lane & 15, q = lane >> 4;
    const int wm = (w >> 1) * 64, wn = (w & 1) * 64;
    const int l8 = lane >> 3, kgsw = (lane & 7) ^ l8;

    // prologue: stage K-steps 0 (buf0) and 1 (buf1)
#pragma unroll
    for (int buf = 0; buf < 2; ++buf)
#pragma unroll
        for (int i = 0; i < 4; ++i) {
            int chunk = w * 4 + i;              // 16 chunks of 8 rows
            int row = chunk * 8 + l8;
            glds16(A  + (size_t)row * 512 + buf * 64 + kgsw * 8, &As[buf * 8192 + chunk * 512]);
            glds16(Bp + (size_t)row * 512 + buf * 64 + kgsw * 8, &Bs[buf * 8192 + chunk * 512]);
        }
    // wait for step-0's 8 loads; keep step-1's 8 in flight
    asm volatile("s_waitcnt vmcnt(8)" ::: "memory");
    asm volatile("s_barrier" ::: "memory");

    for (int it = 0; it < 8; ++it) {
        const __bf16* Ac = As + (it & 1) * 8192;
        const __bf16* Bc = Bs + (it & 1) * 8192;
#pragma unroll
        for (int ks = 0; ks < 2; ++ks) {
            const int koff = ((ks * 4 + q) ^ (c & 7)) * 8;
            bf16x8 af[4], bfr[4];
#pragma unroll
            for (int m = 0; m < 4; ++m)
                af[m] = *(const bf16x8*)&Ac[(wm + m * 16 + c) * 64 + koff];
#pragma unroll
            for (int n = 0; n < 4; ++n)
                bfr[n] = *(const bf16x8*)&Bc[(wn + n * 16 + c) * 64 + koff];
#pragma unroll
            for (int m = 0; m < 4; ++m)
#pragma unroll
                for (int n = 0; n < 4; ++n)
                    acc[m][n] = MFMA16(af[m], bfr[n], acc[m][n]);
        }
        // all waves done reading buf (it&1) -> safe to overwrite
        asm volatile("s_barrier" ::: "memory");
        if (it < 6) {
            int k0n = (it + 2) * 64;
#pragma unroll
            for (int i = 0; i < 4; ++i) {
                int chunk = w * 4 + i;
                int row = chunk * 8 + l8;
                glds16(A  + (size_t)row * 512 + k0n + kgsw * 8, &As[(it & 1) * 8192 + chunk * 512]);
                glds16(Bp + (size_t)row * 512 + k0n + kgsw * 8, &Bs[(it & 1) * 8192 + chunk * 512]);
            }
            // wait for NEXT step's loads; keep the 8 just issued in flight
            asm volatile("s_waitcnt vmcnt(8)" ::: "memory");
        } else {
            asm volatile("s_waitcnt vmcnt(0)" ::: "memory");
        }
        asm volatile("s_barrier" ::: "memory");
    }
}

// ---------------------------------------------------------------------------
// QKV projection. sec 0: q=(Wq hn+bq)*QSCALE -> qT[b][h][l][d]
//                 sec 1: k=(Wkv[0:512] hn+bkv)*SCALE -> kT
//                 sec 2: v=Wkv[512:] hn+bkv[512:] -> v[b][c][l]
// Flat 768-block grid, bijective XCD swizzle: XCD x gets exactly batch x's
// 96 tiles (hn 1 MB + weights L2-resident per XCD).
// ---------------------------------------------------------------------------
__global__ __launch_bounds__(256)
void qkv_kernel(const __bf16* __restrict__ Wq_bf, const __bf16* __restrict__ Wkv_bf,
                const __bf16* __restrict__ hnT,
                const float* __restrict__ bq, const float* __restrict__ bkv,
                __bf16* __restrict__ qT, __bf16* __restrict__ kT,
                __bf16* __restrict__ vv) {
    __shared__ __bf16 SMEM[128 * 64 * 4];       // As(2)|Bs(2), reused as T2
    __bf16* As = SMEM;
    __bf16* Bs = SMEM + 16384;
    const int bid = blockIdx.x;
    const int wgid = (bid & 7) * 96 + (bid >> 3);   // XCD x -> [x*96, x*96+96)
    const int b = wgid / 96;                        // == XCD id
    const int xx = wgid % 96;
    const int sec = xx >> 5, t = xx & 31;
    const __bf16* hb = hnT + (size_t)b * L_ * C_;

    const __bf16 *A, *Bp;
    int m0, n0;
    if (sec < 2) {
        m0 = (t & 3) * 128; n0 = (t >> 2) * 128;    // m=o, n=l
        A  = (sec == 0 ? Wq_bf : Wkv_bf) + (size_t)m0 * 512;
        Bp = hb + (size_t)n0 * 512;
    } else {
        m0 = (t >> 2) * 128; n0 = (t & 3) * 128;    // m=l, n=o
        A  = hb + (size_t)m0 * 512;
        Bp = Wkv_bf + (size_t)(512 + n0) * 512;
    }

    f32x4 acc[4][4];
#pragma unroll
    for (int m = 0; m < 4; ++m)
#pragma unroll
        for (int n = 0; n < 4; ++n)
#pragma unroll
            for (int r = 0; r < 4; ++r) acc[m][n][r] = 0.f;

    gemm_mainloop(A, Bp, As, Bs, acc);          // ends with barrier

    const int tid = threadIdx.x, lane = tid & 63, w = tid >> 6;
    const int c = lane & 15, q = lane >> 4;
    const int wm = (w >> 1) * 64, wn = (w & 1) * 64;

    __bf16* T2 = SMEM;                          // [n_loc 128][m 128], xor-swz
    const float* bias = (sec == 0) ? bq : bkv;
    const float scl = (sec == 0) ? QSCALE : SCALE;
#pragma unroll
    for (int mt = 0; mt < 4; ++mt)
#pragma unroll
        for (int nt = 0; nt < 4; ++nt) {
            int n_loc = wn + nt * 16 + c;
            int u4 = (wm >> 2) + mt * 4 + q;    // 4-elem unit over m
            int u4sw = u4 ^ ((n_loc & 7) << 1);
            bf16x4 ov;
            if (sec < 2) {
                int ob = m0 + wm + mt * 16 + q * 4;
#pragma unroll
                for (int r = 0; r < 4; ++r)
                    ov[r] = (__bf16)((acc[mt][nt][r] + bias[ob + r]) * scl);
            } else {
                float bi = bkv[512 + n0 + n_loc];
#pragma unroll
                for (int r = 0; r < 4; ++r)
                    ov[r] = (__bf16)(acc[mt][nt][r] + bi);
            }
            *(bf16x4*)&T2[n_loc * 128 + u4sw * 4] = ov;
        }
    __syncthreads();
#pragma unroll
    for (int p = 0; p < 8; ++p) {
        int rrow = p * 16 + (tid >> 4);         // n_loc
        int u16 = tid & 15;                     // 8-elem unit over m
        int u4p = (u16 * 2) ^ ((rrow & 7) << 1);
        bf16x8 val = *(const bf16x8*)&T2[rrow * 128 + u4p * 4];
        if (sec < 2) {
            int l = n0 + rrow;
            int og = m0 + u16 * 8;
            int hh = og >> 6, d0 = og & 63;
            __bf16* dstp = (sec == 0) ? qT : kT;
            *(bf16x8*)&dstp[((size_t)(b * NH_ + hh) * L_ + l) * DH_ + d0] = val;
        } else {
            int o = n0 + rrow;
            int lg = m0 + u16 * 8;
            *(bf16x8*)&vv[((size_t)b * C_ + o) * L_ + lg] = val;
        }
    }
}

// ---------------------------------------------------------------------------
// Flash attention v7: 32x32x16 MFMA, in-register softmax, Q direct
// global->register. K/V DOUBLE-buffered (32 KB LDS total): compute buf(it&1);
// B1 (reads done); stage it+2 into the just-freed buf; vmcnt(4) retires tile
// it+1; B2 (resident). __launch_bounds__(256,3) -> 3 blocks/CU = 12 waves/CU.
// l via ones-row MFMA. Flat 512-block grid, batch b -> XCD b (K/V L2-local).
// ---------------------------------------------------------------------------
__global__ __launch_bounds__(256, 3)
void attn_kernel(const __bf16* __restrict__ qT, const __bf16* __restrict__ kT,
                 const __bf16* __restrict__ vv, __bf16* __restrict__ aoT) {
    const int bid = blockIdx.x;
    const int wg = (bid & 7) * 64 + (bid >> 3);     // XCD x -> wg in [x*64,x*64+64)
    const int tt = wg & 7, h = (wg >> 3) & 7, b = wg >> 6;   // b == XCD id
    const int t0 = tt * 128;
    __shared__ __bf16 Ks[2][64 * 64];    // [s][d]  16 KB dbuf
    __shared__ __bf16 Vs[2][64 * 64];    // [d][s]  16 KB dbuf

    const int tid = threadIdx.x, lane = tid & 63, w = tid >> 6;
    const int l8 = lane >> 3, kg = (lane & 7) ^ l8;
    const int ln = lane & 31, hi = lane >> 5, r7 = ln & 7;

    const __bf16* qbase = qT + ((size_t)(b * NH_ + h) * L_ + t0) * DH_;
    const __bf16* kbase = kT + (size_t)(b * NH_ + h) * L_ * DH_;
    const __bf16* vbase = vv + (size_t)(b * C_ + h * DH_) * L_;

    // Q direct to registers: 4 x 16B per lane (L2-hot, qkv just wrote it)
    const int qrow = w * 32 + ln;
    bf16x8 qf[4];
#pragma unroll
    for (int ks = 0; ks < 4; ++ks)
        qf[ks] = *(const bf16x8*)&qbase[(size_t)qrow * DH_ + (ks * 2 + hi) * 8];

    // prefetch K/V tiles 0,1 (2 K-chunks + 2 V-chunks per wave per tile)
#pragma unroll
    for (int buf = 0; buf < 2; ++buf)
#pragma unroll
        for (int i = 0; i < 2; ++i) {
            int chunk = w * 2 + i, row = chunk * 8 + l8;
            glds16(kbase + (size_t)(buf * 64 + row) * DH_ + kg * 8, &Ks[buf][chunk * 512]);
            glds16(vbase + (size_t)row * L_ + buf * 64 + kg * 8, &Vs[buf][chunk * 512]);
        }
    // outstanding: Q(4) + 8 glds16. Retire Q + tile0 (8 oldest); keep tile1.
    asm volatile("s_waitcnt vmcnt(4)" ::: "memory");
    asm volatile("s_barrier" ::: "memory");

    bf16x8 aOnes;                               // A row 0 = ones (l = 1 . P)
    {
        __bf16 one = (__bf16)((ln == 0) ? 1.f : 0.f);
#pragma unroll
        for (int j = 0; j < 8; ++j) aOnes[j] = one;
    }

    f32x16 o_acc[2], o_l;
#pragma unroll
    for (int dt = 0; dt < 2; ++dt)
#pragma unroll
        for (int r = 0; r < 16; ++r) o_acc[dt][r] = 0.f;
#pragma unroll
    for (int r = 0; r < 16; ++r) o_l[r] = 0.f;

    for (int it = 0; it < 16; ++it) {
        const __bf16* Kc = &Ks[it & 1][0];
        const __bf16* Vc = &Vs[it & 1][0];

        // S^T[s][t]: A=K[s][d], B=Q(frags in reg). lane: t=ln, s rows in regs.
        f32x16 sres[2];
#pragma unroll
        for (int mt = 0; mt < 2; ++mt)
#pragma unroll
            for (int r = 0; r < 16; ++r) sres[mt][r] = 0.f;
        __builtin_amdgcn_s_setprio(1);
#pragma unroll
        for (int ks = 0; ks < 4; ++ks) {
#pragma unroll
            for (int mt = 0; mt < 2; ++mt) {
                bf16x8 aK = *(const bf16x8*)&Kc[(mt * 32 + ln) * 64 + ((ks * 2 + hi) ^ r7) * 8];
                sres[mt] = MFMA32(aK, qf[ks], sres[mt]);
            }
        }
        __builtin_amdgcn_s_setprio(0);

        // p = exp2(s); build PV B-fragments in-register.
        // reg r of sres[mt]: s = mt*32 + (r&3) + 8*(r>>2) + 4*hi
        bf16x8 frag[4];
#pragma unroll
        for (int mt = 0; mt < 2; ++mt) {
            float pv[16];
#pragma unroll
            for (int r = 0; r < 16; ++r) pv[r] = exp2f(sres[mt][r]);
            unsigned int P[8];
#pragma unroll
            for (int j = 0; j < 8; ++j)
                asm("v_cvt_pk_bf16_f32 %0, %1, %2" : "=v"(P[j]) : "v"(pv[2 * j]), "v"(pv[2 * j + 1]));
            // after swap: lanes l / l+32 hold complementary s-rows of same t
            asm("v_permlane32_swap_b32 %0, %1" : "+v"(P[0]), "+v"(P[2]));
            asm("v_permlane32_swap_b32 %0, %1" : "+v"(P[1]), "+v"(P[3]));
            asm("v_permlane32_swap_b32 %0, %1" : "+v"(P[4]), "+v"(P[6]));
            asm("v_permlane32_swap_b32 %0, %1" : "+v"(P[5]), "+v"(P[7]));
            union FU { unsigned int u[4]; bf16x8 v; } fa, fb;
            fa.u[0] = P[0]; fa.u[1] = P[1]; fa.u[2] = P[2]; fa.u[3] = P[3];
            fb.u[0] = P[4]; fb.u[1] = P[5]; fb.u[2] = P[6]; fb.u[3] = P[7];
            frag[mt * 2 + 0] = fa.v;            // k = s in [mt*32, mt*32+16)
            frag[mt * 2 + 1] = fb.v;            // k = s in [mt*32+16, mt*32+32)
        }

        // PV: O^T[d][t] += V[d][s] P[t][s];  l[t] += 1 . P[t][:] (row 0)
        __builtin_amdgcn_s_setprio(1);
#pragma unroll
        for (int ks2 = 0; ks2 < 4; ++ks2) {
#pragma unroll
            for (int dt = 0; dt < 2; ++dt) {
                bf16x8 aV = *(const bf16x8*)&Vc[(dt * 32 + ln) * 64 + ((ks2 * 2 + hi) ^ r7) * 8];
                o_acc[dt] = MFMA32(aV, frag[ks2], o_acc[dt]);
            }
            o_l = MFMA32(aOnes, frag[ks2], o_l);
        }
        __builtin_amdgcn_s_setprio(0);

        // B1: all waves done reading buf (it&1) -> safe to overwrite
        asm volatile("s_barrier" ::: "memory");
        if (it < 14) {
            int s0n = (it + 2) * 64;
            __bf16* Kw = &Ks[it & 1][0];
            __bf16* Vw = &Vs[it & 1][0];
#pragma unroll
            for (int i = 0; i < 2; ++i) {
                int chunk = w * 2 + i, row = chunk * 8 + l8;
                glds16(kbase + (size_t)(s0n + row) * DH_ + kg * 8, &Kw[chunk * 512]);
                glds16(vbase + (size_t)row * L_ + s0n + kg * 8, &Vw[chunk * 512]);
            }
            // retire tile it+1 (oldest 4 of 8); keep the 4 just issued
            asm volatile("s_waitcnt vmcnt(4)" ::: "memory");
        } else {
            asm volatile("s_waitcnt vmcnt(0)" ::: "memory");
        }
        asm volatile("s_barrier" ::: "memory");   // B2: tile it+1 resident
    }

    // l[t=ln] sits in reg 0 of lane ln (hi=0 rows of the ones-MFMA output)
    float lsum = __shfl(o_l[0], ln);
    float linv = 1.f / lsum;
    const int tg = t0 + w * 32 + ln;
    __bf16* aobase = aoT + ((size_t)b * L_ + tg) * C_ + h * DH_;
#pragma unroll
    for (int dt = 0; dt < 2; ++dt)
#pragma unroll
        for (int rq = 0; rq < 4; ++rq) {
            bf16x4 ov;
#pragma unroll
            for (int j = 0; j < 4; ++j) ov[j] = (__bf16)(o_acc[dt][rq * 4 + j] * linv);
            *(bf16x4*)&aobase[dt * 32 + rq * 8 + hi * 4] = ov;
        }
}

// ---------------------------------------------------------------------------
// Output projection + bias + residual: D[m=l][n=o], A=aoT, B=Wo. fp32 out.
// Flat 256-block grid, bijective XCD swizzle: XCD x gets batch x's 32 tiles.
// ---------------------------------------------------------------------------
__global__ __launch_bounds__(256)
void proj_kernel(const __bf16* __restrict__ aoT, const __bf16* __restrict__ Wo_bf,
                 const float* __restrict__ bo, const float* __restrict__ x,
                 float* __restrict__ out) {
    __shared__ __bf16 As[2 * 8192], Bs[2 * 8192];
    const int bid = blockIdx.x;
    const int wgid = (bid & 7) * 32 + (bid >> 3);   // XCD x -> [x*32, x*32+32)
    const int b = wgid >> 5, t = wgid & 31;         // b == XCD id
    const int m0 = (t >> 2) * 128;   // l
    const int n0 = (t & 3) * 128;    // o
    const __bf16* A  = aoT + (size_t)b * L_ * C_ + (size_t)m0 * 512;
    const __bf16* Bp = Wo_bf + (size_t)n0 * 512;

    f32x4 acc[4][4];
#pragma unroll
    for (int m = 0; m < 4; ++m)
#pragma unroll
        for (int n = 0; n < 4; ++n)
#pragma unroll
            for (int r = 0; r < 4; ++r) acc[m][n][r] = 0.f;

    gemm_mainloop(A, Bp, As, Bs, acc);

    const int tid = threadIdx.x, lane = tid & 63, w = tid >> 6;
    const int c = lane & 15, q = lane >> 4;
    const int wm = (w >> 1) * 64, wn = (w & 1) * 64;

#pragma unroll
    for (int mt = 0; mt < 4; ++mt)
#pragma unroll
        for (int nt = 0; nt < 4; ++nt) {
            int lb = m0 + wm + mt * 16 + q * 4;  // 4 consecutive l
            int o  = n0 + wn + nt * 16 + c;
            float bi = bo[o];
            size_t off = ((size_t)b * C_ + o) * L_ + lb;
            float4 xv = *(const float4*)&x[off];
            float4 rv;
            rv.x = acc[mt][nt][0] + bi + xv.x;
            rv.y = acc[mt][nt][1] + bi + xv.y;
            rv.z = acc[mt][nt][2] + bi + xv.z;
            rv.w = acc[mt][nt][3] + bi + xv.w;
            *(float4*)&out[off] = rv;
        }
}

// ---------------------------------------------------------------------------
extern "C" void kernel_launch(void* const* d_in, const int* in_sizes, int n_in,
                              void* d_out, int out_size, void* d_ws, size_t ws_size,
                              hipStream_t stream) {
    const float* x     = (const float*)d_in[0];
    const float* gamma = (const float*)d_in[1];
    const float* beta  = (const float*)d_in[2];
    const float* Wq    = (const float*)d_in[3];
    const float* bq    = (const float*)d_in[4];
    const float* Wkv   = (const float*)d_in[5];
    const float* bkv   = (const float*)d_in[6];
    const float* Wo    = (const float*)d_in[7];
    const float* bo    = (const float*)d_in[8];
    float* out = (float*)d_out;

    __bf16* wsb = (__bf16*)d_ws;
    __bf16* Wq_bf  = wsb;                        // 262144
    __bf16* Wkv_bf = wsb + 262144;               // 524288
    __bf16* Wo_bf  = wsb + 786432;               // 262144
    __bf16* hnT    = wsb + 1048576;              // 4 Mi
    __bf16* qT     = wsb + 5242880;              // 4 Mi
    __bf16* kT     = wsb + 9437184;              // 4 Mi
    __bf16* vv     = wsb + 13631488;             // 4 Mi
    __bf16* aoT    = wsb + 17825792;             // 4 Mi
    float*  stats  = (float*)(wsb + 22020096);   // 512 floats

    prep_kernel<<<dim3(1280), 256, 0, stream>>>(Wq, Wkv, Wo, wsb, x, stats);
    gn_apply_kernel<<<dim3(32, B_), 256, 0, stream>>>(x, gamma, beta, stats, hnT);
    qkv_kernel<<<dim3(768), 256, 0, stream>>>(Wq_bf, Wkv_bf, hnT, bq, bkv, qT, kT, vv);
    attn_kernel<<<dim3(512), 256, 0, stream>>>(qT, kT, vv, aoT);
    proj_kernel<<<dim3(256), 256, 0, stream>>>(aoT, Wo_bf, bo, x, out);
}